// Round 6
// baseline (1885.641 us; speedup 1.0000x reference)
//
#include <hip/hip_runtime.h>

#pragma clang fp contract(off)

// TV-L1 optical flow inner scale (TVNet), B=8, H=W=480, 5 warps x 5 iters.
// Fused: one kernel per warp step (warp + 5 inner iterations) with
// spatio-temporal tiling. Region 64x40 per block = tile 54x30 + halo 5.
// 512 threads/block, 5 px/thread, 2 blocks/CU (16 waves/CU).
// LDS holds float2-interleaved state: su={u1,u2}, spA={p11,p21},
// spB={p12,p22} — the neighbor reads in both phases consume exactly these
// pairs, so every 2 scalar LDS ops become one ds_read/write_b64.
// All per-pixel fp arithmetic is op-for-op identical to the passing r4/r5
// versions (JAX-f32 linspace, no FMA contraction, left-to-right
// association) — halo recompute yields bit-identical values.

constexpr int B = 8, H = 480, W = 480;
constexpr int HW = H * W;
constexpr int N = B * HW;

constexpr float THETA = (float)0.3;
constexpr float L_T  = (float)(0.15 * 0.3);   // python f64 product, cast f32
constexpr float TAUT = (float)(0.25 / 0.3);
constexpr float EPSF = (float)1e-12;

#define RW 64              // region width  (LDS tile incl. halo)
#define RH 40              // region height
#define HALO 5
#define TW (RW - 2*HALO)   // 54 output tile width
#define TH (RH - 2*HALO)   // 30 output tile height
#define NTX 9              // ceil(480/54)
#define NTY 16             // 480/30
#define TPB 512
#define NPX (RW*RH/TPB)    // 5 pixels per thread
#define NROW (TPB/RW)      // 8 row-groups

__global__ __launch_bounds__(TPB, 4) void k_fused(
    const float* __restrict__ x1, const float* __restrict__ x2,
    const float* __restrict__ u1In, const float* __restrict__ u2In,
    const float* __restrict__ pIn,          // 4 arrays of N, or nullptr (=0)
    float* __restrict__ u1Out, float* __restrict__ u2Out,
    float* __restrict__ pOut,               // 4 arrays of N
    float* __restrict__ rhoOut, int lastWarp)
{
  __shared__ float2 su[RH][RW];    // {u1, u2}
  __shared__ float2 spA[RH][RW];   // {p11, p21}
  __shared__ float2 spB[RH][RW];   // {p12, p22}

  int blk = blockIdx.x;
  int bx = blk % NTX;
  int by = (blk / NTX) % NTY;
  int b  = blk / (NTX * NTY);
  int ox = bx * TW - HALO;
  int oy = by * TH - HALO;

  int tid = threadIdx.x;
  int lx  = tid & (RW - 1);
  int lyb = tid >> 6;               // 0..7, rows lyb + 8k

  const float* __restrict__ im = x2 + b * HW;
  const int base = b * HW;

  float cdx[NPX], cdy[NPX], crc[NPX];         // dxw, dyw, rho_c
  float ru1[NPX], ru2[NPX];                   // own-pixel u
  float rp11[NPX], rp12[NPX], rp21[NPX], rp22[NPX];  // own-pixel p

  // ---- warp stage: bilinear warp of x2 & its centered gradients ----
#pragma unroll
  for (int k = 0; k < NPX; ++k) {
    int ly = lyb + NROW * k;
    int px = ox + lx, py = oy + ly;
    bool valid = (px >= 0 && px < W && py >= 0 && py < H);
    if (valid) {
      int gi = base + py * W + px;
      float u = u1In[gi], v = u2In[gi];
      // JAX f32 linspace: delta = 2/479 (f32 div), out = -1 + i*delta
      const float step = 2.0f / 479.0f;
      float gx = -1.0f + (float)px * step;
      float gy = -1.0f + (float)py * step;
      float X = ((gx + u * (float)(2.0 / 480.0)) + 1.0f) * 240.0f;
      float Y = ((gy + v * (float)(2.0 / 480.0)) + 1.0f) * 240.0f;
      float fX = floorf(X), fY = floorf(Y);
      int ix = (int)fX, iy = (int)fY;
      int x0i = min(max(ix, 0), W - 1);
      int x1i = min(max(ix + 1, 0), W - 1);
      int y0i = min(max(iy, 0), H - 1);
      int y1i = min(max(iy + 1, 0), H - 1);
      float x0f = (float)x0i, x1f = (float)x1i;
      float y0f = (float)y0i, y1f = (float)y1i;
      float wa = (x1f - X) * (y1f - Y);
      float wb = (x1f - X) * (Y - y0f);
      float wc = (X - x0f) * (y1f - Y);
      float wd = (X - x0f) * (Y - y0f);
      auto at = [&](int yy, int xx) -> float { return im[yy * W + xx]; };
      auto dxc = [&](int yy, int xx) -> float {
        int xm = max(xx - 1, 0), xp = min(xx + 1, W - 1);
        return 0.5f * (at(yy, xp) - at(yy, xm));
      };
      auto dyc = [&](int yy, int xx) -> float {
        int ym = max(yy - 1, 0), yp = min(yy + 1, H - 1);
        return 0.5f * (at(yp, xx) - at(ym, xx));
      };
      float x2w = ((wa * at(y0i, x0i) + wb * at(y1i, x0i)) + wc * at(y0i, x1i)) + wd * at(y1i, x1i);
      float dxw = ((wa * dxc(y0i, x0i) + wb * dxc(y1i, x0i)) + wc * dxc(y0i, x1i)) + wd * dxc(y1i, x1i);
      float dyw = ((wa * dyc(y0i, x0i) + wb * dyc(y1i, x0i)) + wc * dyc(y0i, x1i)) + wd * dyc(y1i, x1i);
      cdx[k] = dxw; cdy[k] = dyw;
      crc[k] = ((x2w - dxw * u) - dyw * v) - x1[gi];
      ru1[k] = u; ru2[k] = v;
      float q11, q12, q21, q22;
      if (pIn) {
        q11 = pIn[0 * N + gi]; q12 = pIn[1 * N + gi];
        q21 = pIn[2 * N + gi]; q22 = pIn[3 * N + gi];
      } else { q11 = 0.f; q12 = 0.f; q21 = 0.f; q22 = 0.f; }
      rp11[k] = q11; rp12[k] = q12; rp21[k] = q21; rp22[k] = q22;
      su[ly][lx]  = make_float2(u, v);
      spA[ly][lx] = make_float2(q11, q21);
      spB[ly][lx] = make_float2(q12, q22);
    }
  }
  __syncthreads();

  // ---- 5 inner iterations, validity boxes shrink by 1/side/iter except
  //      where the region edge is at/past the image boundary ----
  for (int t = 1; t <= 5; ++t) {
    int ulox = ox + t; if (ulox < 0) ulox = 0;
    int uloy = oy + t; if (uloy < 0) uloy = 0;
    int uhix = (ox + RW >= W) ? W : (ox + RW + 1 - t);
    int uhiy = (oy + RH >= H) ? H : (oy + RH + 1 - t);

    // u-phase: reads p (regs + LDS left/up pairs), writes u (regs + LDS)
#pragma unroll
    for (int k = 0; k < NPX; ++k) {
      int ly = lyb + NROW * k;
      int px = ox + lx, py = oy + ly;
      if (px >= ulox && px < uhix && py >= uloy && py < uhiy) {
        float dx = cdx[k], dy = cdy[k];
        float u = ru1[k], v = ru2[k];
        float rho = ((crc[k] + dx * u) + dy * v) + EPSF;
        float grad = (dx * dx + dy * dy) + EPSF;
        float lt_g = L_T * grad;
        float s;
        if (rho < -lt_g)      s = L_T;
        else if (rho > lt_g)  s = -L_T;
        else if (grad > EPSF) s = (-rho) / grad;
        else                  s = 0.f;
        float v1 = s * dx + u;
        float v2 = s * dy + v;
        float2 pl = (px > 0) ? spA[ly][lx - 1] : make_float2(0.f, 0.f);   // {p11,p21} left
        float2 pu = (py > 0) ? spB[ly - 1][lx] : make_float2(0.f, 0.f);   // {p12,p22} up
        float dvx1, dvy1, dvx2, dvy2;
        if (px == 0)          dvx1 = rp11[k];
        else if (px == W - 1) dvx1 = -pl.x;
        else                  dvx1 = rp11[k] - pl.x;
        if (py == 0)          dvy1 = rp12[k];
        else if (py == H - 1) dvy1 = -pu.x;
        else                  dvy1 = rp12[k] - pu.x;
        if (px == 0)          dvx2 = rp21[k];
        else if (px == W - 1) dvx2 = -pl.y;
        else                  dvx2 = rp21[k] - pl.y;
        if (py == 0)          dvy2 = rp22[k];
        else if (py == H - 1) dvy2 = -pu.y;
        else                  dvy2 = rp22[k] - pu.y;
        float nu1 = v1 + THETA * (dvx1 + dvy1);
        float nu2 = v2 + THETA * (dvx2 + dvy2);
        ru1[k] = nu1; ru2[k] = nu2;
        su[ly][lx] = make_float2(nu1, nu2);
        if (lastWarp && t == 5) {
          int tx0 = bx * TW, ty0 = by * TH;
          if (px >= tx0 && px < min(tx0 + TW, W) &&
              py >= ty0 && py < min(ty0 + TH, H))
            rhoOut[base + py * W + px] = rho;
        }
      }
    }
    __syncthreads();

    // p-phase: reads u (regs + LDS right/down pairs), writes p (regs + LDS).
    // Skipped on the last warp's final iteration (p^5 is dead there).
    if (!(lastWarp && t == 5)) {
      int phix = (ox + RW >= W) ? W : (ox + RW - t);
      int phiy = (oy + RH >= H) ? H : (oy + RH - t);
#pragma unroll
      for (int k = 0; k < NPX; ++k) {
        int ly = lyb + NROW * k;
        int px = ox + lx, py = oy + ly;
        if (px >= ulox && px < phix && py >= uloy && py < phiy) {
          float u1c = ru1[k], u2c = ru2[k];
          float2 uR = (px < W - 1) ? su[ly][lx + 1] : make_float2(0.f, 0.f);
          float2 uD = (py < H - 1) ? su[ly + 1][lx] : make_float2(0.f, 0.f);
          float u1x = (px < W - 1) ? uR.x - u1c : 0.f;
          float u1y = (py < H - 1) ? uD.x - u1c : 0.f;
          float u2x = (px < W - 1) ? uR.y - u2c : 0.f;
          float u2y = (py < H - 1) ? uD.y - u2c : 0.f;
          float n1 = 1.0f + TAUT * sqrtf((u1x * u1x + u1y * u1y) + EPSF);
          float n2 = 1.0f + TAUT * sqrtf((u2x * u2x + u2y * u2y) + EPSF);
          float np11 = (rp11[k] + TAUT * u1x) / n1;
          float np12 = (rp12[k] + TAUT * u1y) / n1;
          float np21 = (rp21[k] + TAUT * u2x) / n2;
          float np22 = (rp22[k] + TAUT * u2y) / n2;
          rp11[k] = np11; rp12[k] = np12; rp21[k] = np21; rp22[k] = np22;
          spA[ly][lx] = make_float2(np11, np21);
          spB[ly][lx] = make_float2(np12, np22);
        }
      }
    }
    __syncthreads();
  }

  // ---- write-out: tile pixels only (tiles partition the image) ----
  int tx0 = bx * TW, ty0 = by * TH;
  int tx1 = min(tx0 + TW, W), ty1 = min(ty0 + TH, H);
#pragma unroll
  for (int k = 0; k < NPX; ++k) {
    int ly = lyb + NROW * k;
    int px = ox + lx, py = oy + ly;
    if (px >= tx0 && px < tx1 && py >= ty0 && py < ty1) {
      int gi = base + py * W + px;
      u1Out[gi] = ru1[k];
      u2Out[gi] = ru2[k];
      if (!lastWarp) {
        pOut[0 * N + gi] = rp11[k];
        pOut[1 * N + gi] = rp12[k];
        pOut[2 * N + gi] = rp21[k];
        pOut[3 * N + gi] = rp22[k];
      }
    }
  }
}

extern "C" void kernel_launch(void* const* d_in, const int* in_sizes, int n_in,
                              void* d_out, int out_size, void* d_ws, size_t ws_size,
                              hipStream_t stream) {
  const float* x1 = (const float*)d_in[0];
  const float* x2 = (const float*)d_in[1];
  const float* u1_in = (const float*)d_in[2];
  const float* u2_in = (const float*)d_in[3];

  float* u1o  = (float*)d_out;
  float* u2o  = u1o + (size_t)N;
  float* rhoo = u1o + (size_t)2 * N;

  float* ws  = (float*)d_ws;
  float* uA1 = ws;
  float* uA2 = ws + (size_t)N;
  float* pA  = ws + (size_t)2 * N;   // 4N
  float* uB1 = ws + (size_t)6 * N;
  float* uB2 = ws + (size_t)7 * N;
  float* pB  = ws + (size_t)8 * N;   // 4N (total 12N floats = 88.5 MB)

  dim3 grd(NTX * NTY * B), blk(TPB);
  k_fused<<<grd, blk, 0, stream>>>(x1, x2, u1_in, u2_in, nullptr, uA1, uA2, pA, rhoo, 0);
  k_fused<<<grd, blk, 0, stream>>>(x1, x2, uA1, uA2, pA, uB1, uB2, pB, rhoo, 0);
  k_fused<<<grd, blk, 0, stream>>>(x1, x2, uB1, uB2, pB, uA1, uA2, pA, rhoo, 0);
  k_fused<<<grd, blk, 0, stream>>>(x1, x2, uA1, uA2, pA, uB1, uB2, pB, rhoo, 0);
  k_fused<<<grd, blk, 0, stream>>>(x1, x2, uB1, uB2, pB, u1o, u2o, pA, rhoo, 1);
}

// Round 7
// 383.829 us; speedup vs baseline: 4.9127x; 4.9127x over previous
//
#include <hip/hip_runtime.h>

#pragma clang fp contract(off)

// TV-L1 optical flow inner scale (TVNet), B=8, H=W=480, 5 warps x 5 iters.
// Fused: one kernel per warp step (warp + 5 inner iterations) with
// spatio-temporal tiling. Region 64x40 per block = tile 54x30 + halo 5.
// 512 threads/block, 5 px/thread, 2 blocks/CU (16 waves/CU).
// State u1,u2,p11..p22 lives ONLY in LDS (float2-interleaved: su={u1,u2},
// spA={p11,p21}, spB={p12,p22}); registers hold just the per-pixel warp
// constants cdx,cdy,crc (15 floats) -> no spill under any launch-bounds cap
// (r6 lesson: register copies of LDS state spilled 1 GB/dispatch to scratch).
// All per-pixel fp arithmetic is op-for-op identical to the passing r4/r5
// versions (JAX-f32 linspace, no FMA contraction, left-to-right
// association) — halo recompute yields bit-identical values.

constexpr int B = 8, H = 480, W = 480;
constexpr int HW = H * W;
constexpr int N = B * HW;

constexpr float THETA = (float)0.3;
constexpr float L_T  = (float)(0.15 * 0.3);   // python f64 product, cast f32
constexpr float TAUT = (float)(0.25 / 0.3);
constexpr float EPSF = (float)1e-12;

#define RW 64              // region width  (LDS tile incl. halo)
#define RH 40              // region height
#define HALO 5
#define TW (RW - 2*HALO)   // 54 output tile width
#define TH (RH - 2*HALO)   // 30 output tile height
#define NTX 9              // ceil(480/54)
#define NTY 16             // 480/30
#define TPB 512
#define NPX (RW*RH/TPB)    // 5 pixels per thread
#define NROW (TPB/RW)      // 8 row-groups

__global__ __launch_bounds__(TPB, 4) void k_fused(
    const float* __restrict__ x1, const float* __restrict__ x2,
    const float* __restrict__ u1In, const float* __restrict__ u2In,
    const float* __restrict__ pIn,          // 4 arrays of N, or nullptr (=0)
    float* __restrict__ u1Out, float* __restrict__ u2Out,
    float* __restrict__ pOut,               // 4 arrays of N
    float* __restrict__ rhoOut, int lastWarp)
{
  __shared__ float2 su[RH][RW];    // {u1, u2}
  __shared__ float2 spA[RH][RW];   // {p11, p21}
  __shared__ float2 spB[RH][RW];   // {p12, p22}

  int blk = blockIdx.x;
  int bx = blk % NTX;
  int by = (blk / NTX) % NTY;
  int b  = blk / (NTX * NTY);
  int ox = bx * TW - HALO;
  int oy = by * TH - HALO;

  int tid = threadIdx.x;
  int lx  = tid & (RW - 1);
  int lyb = tid >> 6;               // 0..7, rows lyb + 8k

  const float* __restrict__ im = x2 + b * HW;
  const int base = b * HW;

  float cdx[NPX], cdy[NPX], crc[NPX];   // dxw, dyw, rho_c (only reg state)

  // ---- warp stage: bilinear warp of x2 & its centered gradients ----
#pragma unroll
  for (int k = 0; k < NPX; ++k) {
    int ly = lyb + NROW * k;
    int px = ox + lx, py = oy + ly;
    bool valid = (px >= 0 && px < W && py >= 0 && py < H);
    if (valid) {
      int gi = base + py * W + px;
      float u = u1In[gi], v = u2In[gi];
      // JAX f32 linspace: delta = 2/479 (f32 div), out = -1 + i*delta
      const float step = 2.0f / 479.0f;
      float gx = -1.0f + (float)px * step;
      float gy = -1.0f + (float)py * step;
      float X = ((gx + u * (float)(2.0 / 480.0)) + 1.0f) * 240.0f;
      float Y = ((gy + v * (float)(2.0 / 480.0)) + 1.0f) * 240.0f;
      float fX = floorf(X), fY = floorf(Y);
      int ix = (int)fX, iy = (int)fY;
      int x0i = min(max(ix, 0), W - 1);
      int x1i = min(max(ix + 1, 0), W - 1);
      int y0i = min(max(iy, 0), H - 1);
      int y1i = min(max(iy + 1, 0), H - 1);
      float x0f = (float)x0i, x1f = (float)x1i;
      float y0f = (float)y0i, y1f = (float)y1i;
      float wa = (x1f - X) * (y1f - Y);
      float wb = (x1f - X) * (Y - y0f);
      float wc = (X - x0f) * (y1f - Y);
      float wd = (X - x0f) * (Y - y0f);
      auto at = [&](int yy, int xx) -> float { return im[yy * W + xx]; };
      auto dxc = [&](int yy, int xx) -> float {
        int xm = max(xx - 1, 0), xp = min(xx + 1, W - 1);
        return 0.5f * (at(yy, xp) - at(yy, xm));
      };
      auto dyc = [&](int yy, int xx) -> float {
        int ym = max(yy - 1, 0), yp = min(yy + 1, H - 1);
        return 0.5f * (at(yp, xx) - at(ym, xx));
      };
      float x2w = ((wa * at(y0i, x0i) + wb * at(y1i, x0i)) + wc * at(y0i, x1i)) + wd * at(y1i, x1i);
      float dxw = ((wa * dxc(y0i, x0i) + wb * dxc(y1i, x0i)) + wc * dxc(y0i, x1i)) + wd * dxc(y1i, x1i);
      float dyw = ((wa * dyc(y0i, x0i) + wb * dyc(y1i, x0i)) + wc * dyc(y0i, x1i)) + wd * dyc(y1i, x1i);
      cdx[k] = dxw; cdy[k] = dyw;
      crc[k] = ((x2w - dxw * u) - dyw * v) - x1[gi];
      float q11, q12, q21, q22;
      if (pIn) {
        q11 = pIn[0 * N + gi]; q12 = pIn[1 * N + gi];
        q21 = pIn[2 * N + gi]; q22 = pIn[3 * N + gi];
      } else { q11 = 0.f; q12 = 0.f; q21 = 0.f; q22 = 0.f; }
      su[ly][lx]  = make_float2(u, v);
      spA[ly][lx] = make_float2(q11, q21);
      spB[ly][lx] = make_float2(q12, q22);
    }
  }
  __syncthreads();

  // ---- 5 inner iterations, validity boxes shrink by 1/side/iter except
  //      where the region edge is at/past the image boundary ----
  for (int t = 1; t <= 5; ++t) {
    int ulox = ox + t; if (ulox < 0) ulox = 0;
    int uloy = oy + t; if (uloy < 0) uloy = 0;
    int uhix = (ox + RW >= W) ? W : (ox + RW + 1 - t);
    int uhiy = (oy + RH >= H) ? H : (oy + RH + 1 - t);

    // u-phase: reads own u/p + left/up p pairs (LDS), writes u (LDS)
#pragma unroll
    for (int k = 0; k < NPX; ++k) {
      int ly = lyb + NROW * k;
      int px = ox + lx, py = oy + ly;
      if (px >= ulox && px < uhix && py >= uloy && py < uhiy) {
        float2 uo  = su[ly][lx];
        float2 pAo = spA[ly][lx];     // {p11, p21} own
        float2 pBo = spB[ly][lx];     // {p12, p22} own
        // in-window => lx>=1, ly>=1 (halo), so indices are safe; values
        // unused when px==0 / py==0 (boundary branch below)
        float2 pl = spA[ly][lx - 1];  // {p11, p21} left
        float2 pu = spB[ly - 1][lx];  // {p12, p22} up
        float dx = cdx[k], dy = cdy[k];
        float u = uo.x, v = uo.y;
        float rho = ((crc[k] + dx * u) + dy * v) + EPSF;
        float grad = (dx * dx + dy * dy) + EPSF;
        float lt_g = L_T * grad;
        float s;
        if (rho < -lt_g)      s = L_T;
        else if (rho > lt_g)  s = -L_T;
        else if (grad > EPSF) s = (-rho) / grad;
        else                  s = 0.f;
        float v1 = s * dx + u;
        float v2 = s * dy + v;
        float dvx1, dvy1, dvx2, dvy2;
        if (px == 0)          dvx1 = pAo.x;
        else if (px == W - 1) dvx1 = -pl.x;
        else                  dvx1 = pAo.x - pl.x;
        if (py == 0)          dvy1 = pBo.x;
        else if (py == H - 1) dvy1 = -pu.x;
        else                  dvy1 = pBo.x - pu.x;
        if (px == 0)          dvx2 = pAo.y;
        else if (px == W - 1) dvx2 = -pl.y;
        else                  dvx2 = pAo.y - pl.y;
        if (py == 0)          dvy2 = pBo.y;
        else if (py == H - 1) dvy2 = -pu.y;
        else                  dvy2 = pBo.y - pu.y;
        float nu1 = v1 + THETA * (dvx1 + dvy1);
        float nu2 = v2 + THETA * (dvx2 + dvy2);
        su[ly][lx] = make_float2(nu1, nu2);
        if (lastWarp && t == 5) {
          int tx0 = bx * TW, ty0 = by * TH;
          if (px >= tx0 && px < min(tx0 + TW, W) &&
              py >= ty0 && py < min(ty0 + TH, H))
            rhoOut[base + py * W + px] = rho;
        }
      }
    }
    __syncthreads();

    // p-phase: reads own/right/down u + own p (LDS), writes p (LDS).
    // Skipped on the last warp's final iteration (p^5 is dead there).
    if (!(lastWarp && t == 5)) {
      int phix = (ox + RW >= W) ? W : (ox + RW - t);
      int phiy = (oy + RH >= H) ? H : (oy + RH - t);
#pragma unroll
      for (int k = 0; k < NPX; ++k) {
        int ly = lyb + NROW * k;
        int px = ox + lx, py = oy + ly;
        if (px >= ulox && px < phix && py >= uloy && py < phiy) {
          float2 uo = su[ly][lx];
          float2 uR = su[ly][lx + 1];   // unused when px==W-1 (pad-safe)
          float2 uD = su[ly + 1][lx];   // unused when py==H-1
          float2 pAo = spA[ly][lx];
          float2 pBo = spB[ly][lx];
          float u1c = uo.x, u2c = uo.y;
          float u1x = (px < W - 1) ? uR.x - u1c : 0.f;
          float u1y = (py < H - 1) ? uD.x - u1c : 0.f;
          float u2x = (px < W - 1) ? uR.y - u2c : 0.f;
          float u2y = (py < H - 1) ? uD.y - u2c : 0.f;
          float n1 = 1.0f + TAUT * sqrtf((u1x * u1x + u1y * u1y) + EPSF);
          float n2 = 1.0f + TAUT * sqrtf((u2x * u2x + u2y * u2y) + EPSF);
          float np11 = (pAo.x + TAUT * u1x) / n1;
          float np12 = (pBo.x + TAUT * u1y) / n1;
          float np21 = (pAo.y + TAUT * u2x) / n2;
          float np22 = (pBo.y + TAUT * u2y) / n2;
          spA[ly][lx] = make_float2(np11, np21);
          spB[ly][lx] = make_float2(np12, np22);
        }
      }
    }
    __syncthreads();
  }

  // ---- write-out: tile pixels only (tiles partition the image) ----
  int tx0 = bx * TW, ty0 = by * TH;
  int tx1 = min(tx0 + TW, W), ty1 = min(ty0 + TH, H);
#pragma unroll
  for (int k = 0; k < NPX; ++k) {
    int ly = lyb + NROW * k;
    int px = ox + lx, py = oy + ly;
    if (px >= tx0 && px < tx1 && py >= ty0 && py < ty1) {
      int gi = base + py * W + px;
      float2 uo = su[ly][lx];
      u1Out[gi] = uo.x;
      u2Out[gi] = uo.y;
      if (!lastWarp) {
        float2 pAo = spA[ly][lx];
        float2 pBo = spB[ly][lx];
        pOut[0 * N + gi] = pAo.x;
        pOut[1 * N + gi] = pBo.x;
        pOut[2 * N + gi] = pAo.y;
        pOut[3 * N + gi] = pBo.y;
      }
    }
  }
}

extern "C" void kernel_launch(void* const* d_in, const int* in_sizes, int n_in,
                              void* d_out, int out_size, void* d_ws, size_t ws_size,
                              hipStream_t stream) {
  const float* x1 = (const float*)d_in[0];
  const float* x2 = (const float*)d_in[1];
  const float* u1_in = (const float*)d_in[2];
  const float* u2_in = (const float*)d_in[3];

  float* u1o  = (float*)d_out;
  float* u2o  = u1o + (size_t)N;
  float* rhoo = u1o + (size_t)2 * N;

  float* ws  = (float*)d_ws;
  float* uA1 = ws;
  float* uA2 = ws + (size_t)N;
  float* pA  = ws + (size_t)2 * N;   // 4N
  float* uB1 = ws + (size_t)6 * N;
  float* uB2 = ws + (size_t)7 * N;
  float* pB  = ws + (size_t)8 * N;   // 4N (total 12N floats = 88.5 MB)

  dim3 grd(NTX * NTY * B), blk(TPB);
  k_fused<<<grd, blk, 0, stream>>>(x1, x2, u1_in, u2_in, nullptr, uA1, uA2, pA, rhoo, 0);
  k_fused<<<grd, blk, 0, stream>>>(x1, x2, uA1, uA2, pA, uB1, uB2, pB, rhoo, 0);
  k_fused<<<grd, blk, 0, stream>>>(x1, x2, uB1, uB2, pB, uA1, uA2, pA, rhoo, 0);
  k_fused<<<grd, blk, 0, stream>>>(x1, x2, uA1, uA2, pA, uB1, uB2, pB, rhoo, 0);
  k_fused<<<grd, blk, 0, stream>>>(x1, x2, uB1, uB2, pB, u1o, u2o, pA, rhoo, 1);
}

// Round 8
// 367.893 us; speedup vs baseline: 5.1255x; 1.0433x over previous
//
#include <hip/hip_runtime.h>

#pragma clang fp contract(off)

// TV-L1 optical flow inner scale (TVNet), B=8, H=W=480, 5 warps x 5 iters.
// Fused: one kernel per warp step (warp + 5 inner iterations) with
// spatio-temporal tiling. Region 64x32 per block = tile 54x22 + halo 5.
// 512 threads/block, 4 px/thread, 3 blocks/CU (24 waves/CU, LDS 48K x3).
// State u1,u2,p11..p22 lives ONLY in LDS (float2-interleaved: su={u1,u2},
// spA={p11,p21}, spB={p12,p22}); registers hold just the per-pixel warp
// constants cdx,cdy,crc (12 floats) -> no spill (r6 lesson).
// All per-pixel fp arithmetic is op-for-op identical to the passing r4-r7
// versions (JAX-f32 linspace, no FMA contraction, left-to-right
// association) — halo recompute yields bit-identical values.

constexpr int B = 8, H = 480, W = 480;
constexpr int HW = H * W;
constexpr int N = B * HW;

constexpr float THETA = (float)0.3;
constexpr float L_T  = (float)(0.15 * 0.3);   // python f64 product, cast f32
constexpr float TAUT = (float)(0.25 / 0.3);
constexpr float EPSF = (float)1e-12;

#define RW 64              // region width  (LDS tile incl. halo)
#define RH 32              // region height
#define HALO 5
#define TW (RW - 2*HALO)   // 54 output tile width
#define TH (RH - 2*HALO)   // 22 output tile height
#define NTX 9              // ceil(480/54)
#define NTY 22             // ceil(480/22)
#define TPB 512
#define NPX (RW*RH/TPB)    // 4 pixels per thread
#define NROW (TPB/RW)      // 8 row-groups

__global__ __launch_bounds__(TPB, 4) void k_fused(
    const float* __restrict__ x1, const float* __restrict__ x2,
    const float* __restrict__ u1In, const float* __restrict__ u2In,
    const float* __restrict__ pIn,          // 4 arrays of N, or nullptr (=0)
    float* __restrict__ u1Out, float* __restrict__ u2Out,
    float* __restrict__ pOut,               // 4 arrays of N
    float* __restrict__ rhoOut, int lastWarp)
{
  __shared__ float2 su[RH][RW];    // {u1, u2}
  __shared__ float2 spA[RH][RW];   // {p11, p21}
  __shared__ float2 spB[RH][RW];   // {p12, p22}

  int blk = blockIdx.x;
  int bx = blk % NTX;
  int by = (blk / NTX) % NTY;
  int b  = blk / (NTX * NTY);
  int ox = bx * TW - HALO;
  int oy = by * TH - HALO;

  int tid = threadIdx.x;
  int lx  = tid & (RW - 1);
  int lyb = tid >> 6;               // 0..7, rows lyb + 8k

  const float* __restrict__ im = x2 + b * HW;
  const int base = b * HW;

  float cdx[NPX], cdy[NPX], crc[NPX];   // dxw, dyw, rho_c (only reg state)

  // ---- warp stage: bilinear warp of x2 & its centered gradients ----
#pragma unroll
  for (int k = 0; k < NPX; ++k) {
    int ly = lyb + NROW * k;
    int px = ox + lx, py = oy + ly;
    bool valid = (px >= 0 && px < W && py >= 0 && py < H);
    if (valid) {
      int gi = base + py * W + px;
      float u = u1In[gi], v = u2In[gi];
      // JAX f32 linspace: delta = 2/479 (f32 div), out = -1 + i*delta
      const float step = 2.0f / 479.0f;
      float gx = -1.0f + (float)px * step;
      float gy = -1.0f + (float)py * step;
      float X = ((gx + u * (float)(2.0 / 480.0)) + 1.0f) * 240.0f;
      float Y = ((gy + v * (float)(2.0 / 480.0)) + 1.0f) * 240.0f;
      float fX = floorf(X), fY = floorf(Y);
      int ix = (int)fX, iy = (int)fY;
      int x0i = min(max(ix, 0), W - 1);
      int x1i = min(max(ix + 1, 0), W - 1);
      int y0i = min(max(iy, 0), H - 1);
      int y1i = min(max(iy + 1, 0), H - 1);
      float x0f = (float)x0i, x1f = (float)x1i;
      float y0f = (float)y0i, y1f = (float)y1i;
      float wa = (x1f - X) * (y1f - Y);
      float wb = (x1f - X) * (Y - y0f);
      float wc = (X - x0f) * (y1f - Y);
      float wd = (X - x0f) * (Y - y0f);
      auto at = [&](int yy, int xx) -> float { return im[yy * W + xx]; };
      auto dxc = [&](int yy, int xx) -> float {
        int xm = max(xx - 1, 0), xp = min(xx + 1, W - 1);
        return 0.5f * (at(yy, xp) - at(yy, xm));
      };
      auto dyc = [&](int yy, int xx) -> float {
        int ym = max(yy - 1, 0), yp = min(yy + 1, H - 1);
        return 0.5f * (at(yp, xx) - at(ym, xx));
      };
      float x2w = ((wa * at(y0i, x0i) + wb * at(y1i, x0i)) + wc * at(y0i, x1i)) + wd * at(y1i, x1i);
      float dxw = ((wa * dxc(y0i, x0i) + wb * dxc(y1i, x0i)) + wc * dxc(y0i, x1i)) + wd * dxc(y1i, x1i);
      float dyw = ((wa * dyc(y0i, x0i) + wb * dyc(y1i, x0i)) + wc * dyc(y0i, x1i)) + wd * dyc(y1i, x1i);
      cdx[k] = dxw; cdy[k] = dyw;
      crc[k] = ((x2w - dxw * u) - dyw * v) - x1[gi];
      float q11, q12, q21, q22;
      if (pIn) {
        q11 = pIn[0 * N + gi]; q12 = pIn[1 * N + gi];
        q21 = pIn[2 * N + gi]; q22 = pIn[3 * N + gi];
      } else { q11 = 0.f; q12 = 0.f; q21 = 0.f; q22 = 0.f; }
      su[ly][lx]  = make_float2(u, v);
      spA[ly][lx] = make_float2(q11, q21);
      spB[ly][lx] = make_float2(q12, q22);
    }
  }
  __syncthreads();

  // ---- 5 inner iterations, validity boxes shrink by 1/side/iter except
  //      where the region edge is at/past the image boundary ----
  for (int t = 1; t <= 5; ++t) {
    int ulox = ox + t; if (ulox < 0) ulox = 0;
    int uloy = oy + t; if (uloy < 0) uloy = 0;
    int uhix = (ox + RW >= W) ? W : (ox + RW + 1 - t);
    int uhiy = (oy + RH >= H) ? H : (oy + RH + 1 - t);

    // u-phase: reads own u/p + left/up p pairs (LDS), writes u (LDS)
#pragma unroll
    for (int k = 0; k < NPX; ++k) {
      int ly = lyb + NROW * k;
      int px = ox + lx, py = oy + ly;
      if (px >= ulox && px < uhix && py >= uloy && py < uhiy) {
        float2 uo  = su[ly][lx];
        float2 pAo = spA[ly][lx];     // {p11, p21} own
        float2 pBo = spB[ly][lx];     // {p12, p22} own
        // in-window => lx>=1, ly>=1 (halo), so indices are safe; values
        // unused when px==0 / py==0 (boundary branch below)
        float2 pl = spA[ly][lx - 1];  // {p11, p21} left
        float2 pu = spB[ly - 1][lx];  // {p12, p22} up
        float dx = cdx[k], dy = cdy[k];
        float u = uo.x, v = uo.y;
        float rho = ((crc[k] + dx * u) + dy * v) + EPSF;
        float grad = (dx * dx + dy * dy) + EPSF;
        float lt_g = L_T * grad;
        float s;
        if (rho < -lt_g)      s = L_T;
        else if (rho > lt_g)  s = -L_T;
        else if (grad > EPSF) s = (-rho) / grad;
        else                  s = 0.f;
        float v1 = s * dx + u;
        float v2 = s * dy + v;
        float dvx1, dvy1, dvx2, dvy2;
        if (px == 0)          dvx1 = pAo.x;
        else if (px == W - 1) dvx1 = -pl.x;
        else                  dvx1 = pAo.x - pl.x;
        if (py == 0)          dvy1 = pBo.x;
        else if (py == H - 1) dvy1 = -pu.x;
        else                  dvy1 = pBo.x - pu.x;
        if (px == 0)          dvx2 = pAo.y;
        else if (px == W - 1) dvx2 = -pl.y;
        else                  dvx2 = pAo.y - pl.y;
        if (py == 0)          dvy2 = pBo.y;
        else if (py == H - 1) dvy2 = -pu.y;
        else                  dvy2 = pBo.y - pu.y;
        float nu1 = v1 + THETA * (dvx1 + dvy1);
        float nu2 = v2 + THETA * (dvx2 + dvy2);
        su[ly][lx] = make_float2(nu1, nu2);
        if (lastWarp && t == 5) {
          int tx0 = bx * TW, ty0 = by * TH;
          if (px >= tx0 && px < min(tx0 + TW, W) &&
              py >= ty0 && py < min(ty0 + TH, H))
            rhoOut[base + py * W + px] = rho;
        }
      }
    }
    __syncthreads();

    // p-phase: reads own/right/down u + own p (LDS), writes p (LDS).
    // Skipped on the last warp's final iteration (p^5 is dead there).
    if (!(lastWarp && t == 5)) {
      int phix = (ox + RW >= W) ? W : (ox + RW - t);
      int phiy = (oy + RH >= H) ? H : (oy + RH - t);
#pragma unroll
      for (int k = 0; k < NPX; ++k) {
        int ly = lyb + NROW * k;
        int px = ox + lx, py = oy + ly;
        if (px >= ulox && px < phix && py >= uloy && py < phiy) {
          float2 uo = su[ly][lx];
          float2 uR = su[ly][lx + 1];   // unused when px==W-1 (pad-safe)
          float2 uD = su[ly + 1][lx];   // unused when py==H-1
          float2 pAo = spA[ly][lx];
          float2 pBo = spB[ly][lx];
          float u1c = uo.x, u2c = uo.y;
          float u1x = (px < W - 1) ? uR.x - u1c : 0.f;
          float u1y = (py < H - 1) ? uD.x - u1c : 0.f;
          float u2x = (px < W - 1) ? uR.y - u2c : 0.f;
          float u2y = (py < H - 1) ? uD.y - u2c : 0.f;
          float n1 = 1.0f + TAUT * sqrtf((u1x * u1x + u1y * u1y) + EPSF);
          float n2 = 1.0f + TAUT * sqrtf((u2x * u2x + u2y * u2y) + EPSF);
          float np11 = (pAo.x + TAUT * u1x) / n1;
          float np12 = (pBo.x + TAUT * u1y) / n1;
          float np21 = (pAo.y + TAUT * u2x) / n2;
          float np22 = (pBo.y + TAUT * u2y) / n2;
          spA[ly][lx] = make_float2(np11, np21);
          spB[ly][lx] = make_float2(np12, np22);
        }
      }
    }
    __syncthreads();
  }

  // ---- write-out: tile pixels only (tiles partition the image) ----
  int tx0 = bx * TW, ty0 = by * TH;
  int tx1 = min(tx0 + TW, W), ty1 = min(ty0 + TH, H);
#pragma unroll
  for (int k = 0; k < NPX; ++k) {
    int ly = lyb + NROW * k;
    int px = ox + lx, py = oy + ly;
    if (px >= tx0 && px < tx1 && py >= ty0 && py < ty1) {
      int gi = base + py * W + px;
      float2 uo = su[ly][lx];
      u1Out[gi] = uo.x;
      u2Out[gi] = uo.y;
      if (!lastWarp) {
        float2 pAo = spA[ly][lx];
        float2 pBo = spB[ly][lx];
        pOut[0 * N + gi] = pAo.x;
        pOut[1 * N + gi] = pBo.x;
        pOut[2 * N + gi] = pAo.y;
        pOut[3 * N + gi] = pBo.y;
      }
    }
  }
}

extern "C" void kernel_launch(void* const* d_in, const int* in_sizes, int n_in,
                              void* d_out, int out_size, void* d_ws, size_t ws_size,
                              hipStream_t stream) {
  const float* x1 = (const float*)d_in[0];
  const float* x2 = (const float*)d_in[1];
  const float* u1_in = (const float*)d_in[2];
  const float* u2_in = (const float*)d_in[3];

  float* u1o  = (float*)d_out;
  float* u2o  = u1o + (size_t)N;
  float* rhoo = u1o + (size_t)2 * N;

  float* ws  = (float*)d_ws;
  float* uA1 = ws;
  float* uA2 = ws + (size_t)N;
  float* pA  = ws + (size_t)2 * N;   // 4N
  float* uB1 = ws + (size_t)6 * N;
  float* uB2 = ws + (size_t)7 * N;
  float* pB  = ws + (size_t)8 * N;   // 4N (total 12N floats = 88.5 MB)

  dim3 grd(NTX * NTY * B), blk(TPB);
  k_fused<<<grd, blk, 0, stream>>>(x1, x2, u1_in, u2_in, nullptr, uA1, uA2, pA, rhoo, 0);
  k_fused<<<grd, blk, 0, stream>>>(x1, x2, uA1, uA2, pA, uB1, uB2, pB, rhoo, 0);
  k_fused<<<grd, blk, 0, stream>>>(x1, x2, uB1, uB2, pB, uA1, uA2, pA, rhoo, 0);
  k_fused<<<grd, blk, 0, stream>>>(x1, x2, uA1, uA2, pA, uB1, uB2, pB, rhoo, 0);
  k_fused<<<grd, blk, 0, stream>>>(x1, x2, uB1, uB2, pB, u1o, u2o, pA, rhoo, 1);
}

// Round 9
// 354.474 us; speedup vs baseline: 5.3195x; 1.0379x over previous
//
#include <hip/hip_runtime.h>

#pragma clang fp contract(off)

// TV-L1 optical flow inner scale (TVNet), B=8, H=W=480, 5 warps x 5 iters.
// Fused: one kernel per warp step (warp + 5 inner iterations) with
// spatio-temporal tiling. Region 50x40 per block = tile 40x30 + halo 5.
// Grid = 12x16x8 = 1536 blocks = EXACTLY 2 rounds of 768 co-resident
// (3 blocks/CU x 256 CU) -> no scheduling tail (r8 lesson: 1584 blocks
// = 2.06 rounds cost a 3rd, 94%-idle round).
// 512 threads/block, 4 px/thread via linear idx (ly=idx/50, lx=idx%50).
// State u1,u2,p11..p22 lives ONLY in LDS (float2-interleaved: su={u1,u2},
// spA={p11,p21}, spB={p12,p22}); registers hold just cdx,cdy,crc.
// All per-pixel fp arithmetic is op-for-op identical to the passing r4-r8
// versions (JAX-f32 linspace, no FMA contraction, left-to-right
// association) — halo recompute yields bit-identical values.

constexpr int B = 8, H = 480, W = 480;
constexpr int HW = H * W;
constexpr int N = B * HW;

constexpr float THETA = (float)0.3;
constexpr float L_T  = (float)(0.15 * 0.3);   // python f64 product, cast f32
constexpr float TAUT = (float)(0.25 / 0.3);
constexpr float EPSF = (float)1e-12;

#define RW 50              // region width  (LDS tile incl. halo)
#define RH 40              // region height
#define HALO 5
#define TW (RW - 2*HALO)   // 40 output tile width
#define TH (RH - 2*HALO)   // 30 output tile height
#define NTX 12             // 480/40
#define NTY 16             // 480/30
#define TPB 512
#define NPX 4              // ceil(50*40/512); k==3 partial (idx<2000)
#define RPX (RW*RH)        // 2000 region pixels

template <int LASTWARP>
__global__ __launch_bounds__(TPB, 4) void k_fused(
    const float* __restrict__ x1, const float* __restrict__ x2,
    const float* __restrict__ u1In, const float* __restrict__ u2In,
    const float* __restrict__ pIn,          // 4 arrays of N, or nullptr (=0)
    float* __restrict__ u1Out, float* __restrict__ u2Out,
    float* __restrict__ pOut,               // 4 arrays of N
    float* __restrict__ rhoOut)
{
  __shared__ float2 su[RH][RW];    // {u1, u2}
  __shared__ float2 spA[RH][RW];   // {p11, p21}
  __shared__ float2 spB[RH][RW];   // {p12, p22}

  int blk = blockIdx.x;
  int bx = blk % NTX;
  int by = (blk / NTX) % NTY;
  int b  = blk / (NTX * NTY);
  int ox = bx * TW - HALO;
  int oy = by * TH - HALO;

  int tid = threadIdx.x;

  const float* __restrict__ im = x2 + b * HW;
  const int base = b * HW;

  float cdx[NPX], cdy[NPX], crc[NPX];   // dxw, dyw, rho_c (only reg state)

  // ---- warp stage: bilinear warp of x2 & its centered gradients ----
#pragma unroll
  for (int k = 0; k < NPX; ++k) {
    int idx = tid + k * TPB;
    if (idx < RPX) {
      int ly = idx / RW, lx = idx - ly * RW;
      int px = ox + lx, py = oy + ly;
      bool valid = (px >= 0 && px < W && py >= 0 && py < H);
      if (valid) {
        int gi = base + py * W + px;
        float u = u1In[gi], v = u2In[gi];
        // JAX f32 linspace: delta = 2/479 (f32 div), out = -1 + i*delta
        const float step = 2.0f / 479.0f;
        float gx = -1.0f + (float)px * step;
        float gy = -1.0f + (float)py * step;
        float X = ((gx + u * (float)(2.0 / 480.0)) + 1.0f) * 240.0f;
        float Y = ((gy + v * (float)(2.0 / 480.0)) + 1.0f) * 240.0f;
        float fX = floorf(X), fY = floorf(Y);
        int ix = (int)fX, iy = (int)fY;
        int x0i = min(max(ix, 0), W - 1);
        int x1i = min(max(ix + 1, 0), W - 1);
        int y0i = min(max(iy, 0), H - 1);
        int y1i = min(max(iy + 1, 0), H - 1);
        float x0f = (float)x0i, x1f = (float)x1i;
        float y0f = (float)y0i, y1f = (float)y1i;
        float wa = (x1f - X) * (y1f - Y);
        float wb = (x1f - X) * (Y - y0f);
        float wc = (X - x0f) * (y1f - Y);
        float wd = (X - x0f) * (Y - y0f);
        auto at = [&](int yy, int xx) -> float { return im[yy * W + xx]; };
        auto dxc = [&](int yy, int xx) -> float {
          int xm = max(xx - 1, 0), xp = min(xx + 1, W - 1);
          return 0.5f * (at(yy, xp) - at(yy, xm));
        };
        auto dyc = [&](int yy, int xx) -> float {
          int ym = max(yy - 1, 0), yp = min(yy + 1, H - 1);
          return 0.5f * (at(yp, xx) - at(ym, xx));
        };
        float x2w = ((wa * at(y0i, x0i) + wb * at(y1i, x0i)) + wc * at(y0i, x1i)) + wd * at(y1i, x1i);
        float dxw = ((wa * dxc(y0i, x0i) + wb * dxc(y1i, x0i)) + wc * dxc(y0i, x1i)) + wd * dxc(y1i, x1i);
        float dyw = ((wa * dyc(y0i, x0i) + wb * dyc(y1i, x0i)) + wc * dyc(y0i, x1i)) + wd * dyc(y1i, x1i);
        cdx[k] = dxw; cdy[k] = dyw;
        crc[k] = ((x2w - dxw * u) - dyw * v) - x1[gi];
        float q11, q12, q21, q22;
        if (pIn) {
          q11 = pIn[0 * N + gi]; q12 = pIn[1 * N + gi];
          q21 = pIn[2 * N + gi]; q22 = pIn[3 * N + gi];
        } else { q11 = 0.f; q12 = 0.f; q21 = 0.f; q22 = 0.f; }
        su[ly][lx]  = make_float2(u, v);
        spA[ly][lx] = make_float2(q11, q21);
        spB[ly][lx] = make_float2(q12, q22);
      }
    }
  }
  __syncthreads();

  // ---- 5 inner iterations, validity boxes shrink by 1/side/iter except
  //      where the region edge is at/past the image boundary ----
  for (int t = 1; t <= 5; ++t) {
    int ulox = ox + t; if (ulox < 0) ulox = 0;
    int uloy = oy + t; if (uloy < 0) uloy = 0;
    int uhix = (ox + RW >= W) ? W : (ox + RW + 1 - t);
    int uhiy = (oy + RH >= H) ? H : (oy + RH + 1 - t);

    // u-phase: reads own u/p + left/up p pairs (LDS), writes u (LDS)
#pragma unroll
    for (int k = 0; k < NPX; ++k) {
      int idx = tid + k * TPB;
      if (idx < RPX) {
        int ly = idx / RW, lx = idx - ly * RW;
        int px = ox + lx, py = oy + ly;
        if (px >= ulox && px < uhix && py >= uloy && py < uhiy) {
          float2 uo  = su[ly][lx];
          float2 pAo = spA[ly][lx];     // {p11, p21} own
          float2 pBo = spB[ly][lx];     // {p12, p22} own
          // in-window => lx>=1, ly>=1 (halo), so indices are safe; values
          // unused when px==0 / py==0 (boundary branch below)
          float2 pl = spA[ly][lx - 1];  // {p11, p21} left
          float2 pu = spB[ly - 1][lx];  // {p12, p22} up
          float dx = cdx[k], dy = cdy[k];
          float u = uo.x, v = uo.y;
          float rho = ((crc[k] + dx * u) + dy * v) + EPSF;
          float grad = (dx * dx + dy * dy) + EPSF;
          float lt_g = L_T * grad;
          float s;
          if (rho < -lt_g)      s = L_T;
          else if (rho > lt_g)  s = -L_T;
          else if (grad > EPSF) s = (-rho) / grad;
          else                  s = 0.f;
          float v1 = s * dx + u;
          float v2 = s * dy + v;
          float dvx1, dvy1, dvx2, dvy2;
          if (px == 0)          dvx1 = pAo.x;
          else if (px == W - 1) dvx1 = -pl.x;
          else                  dvx1 = pAo.x - pl.x;
          if (py == 0)          dvy1 = pBo.x;
          else if (py == H - 1) dvy1 = -pu.x;
          else                  dvy1 = pBo.x - pu.x;
          if (px == 0)          dvx2 = pAo.y;
          else if (px == W - 1) dvx2 = -pl.y;
          else                  dvx2 = pAo.y - pl.y;
          if (py == 0)          dvy2 = pBo.y;
          else if (py == H - 1) dvy2 = -pu.y;
          else                  dvy2 = pBo.y - pu.y;
          float nu1 = v1 + THETA * (dvx1 + dvy1);
          float nu2 = v2 + THETA * (dvx2 + dvy2);
          su[ly][lx] = make_float2(nu1, nu2);
          if (LASTWARP && t == 5) {
            int tx0 = bx * TW, ty0 = by * TH;
            if (px >= tx0 && px < tx0 + TW && py >= ty0 && py < ty0 + TH)
              rhoOut[base + py * W + px] = rho;
          }
        }
      }
    }
    __syncthreads();

    // p-phase: reads own/right/down u + own p (LDS), writes p (LDS).
    // Skipped on the last warp's final iteration (p^5 is dead there).
    if (!(LASTWARP && t == 5)) {
      int phix = (ox + RW >= W) ? W : (ox + RW - t);
      int phiy = (oy + RH >= H) ? H : (oy + RH - t);
#pragma unroll
      for (int k = 0; k < NPX; ++k) {
        int idx = tid + k * TPB;
        if (idx < RPX) {
          int ly = idx / RW, lx = idx - ly * RW;
          int px = ox + lx, py = oy + ly;
          if (px >= ulox && px < phix && py >= uloy && py < phiy) {
            float2 uo = su[ly][lx];
            float2 uR = su[ly][lx + 1];   // unused when px==W-1 (pad-safe)
            float2 uD = su[ly + 1][lx];   // unused when py==H-1
            float2 pAo = spA[ly][lx];
            float2 pBo = spB[ly][lx];
            float u1c = uo.x, u2c = uo.y;
            float u1x = (px < W - 1) ? uR.x - u1c : 0.f;
            float u1y = (py < H - 1) ? uD.x - u1c : 0.f;
            float u2x = (px < W - 1) ? uR.y - u2c : 0.f;
            float u2y = (py < H - 1) ? uD.y - u2c : 0.f;
            float n1 = 1.0f + TAUT * sqrtf((u1x * u1x + u1y * u1y) + EPSF);
            float n2 = 1.0f + TAUT * sqrtf((u2x * u2x + u2y * u2y) + EPSF);
            float np11 = (pAo.x + TAUT * u1x) / n1;
            float np12 = (pBo.x + TAUT * u1y) / n1;
            float np21 = (pAo.y + TAUT * u2x) / n2;
            float np22 = (pBo.y + TAUT * u2y) / n2;
            spA[ly][lx] = make_float2(np11, np21);
            spB[ly][lx] = make_float2(np12, np22);
          }
        }
      }
    }
    __syncthreads();
  }

  // ---- write-out: tile pixels only (tiles partition the image exactly) ----
  int tx0 = bx * TW, ty0 = by * TH;
#pragma unroll
  for (int k = 0; k < NPX; ++k) {
    int idx = tid + k * TPB;
    if (idx < RPX) {
      int ly = idx / RW, lx = idx - ly * RW;
      int px = ox + lx, py = oy + ly;
      if (px >= tx0 && px < tx0 + TW && py >= ty0 && py < ty0 + TH) {
        int gi = base + py * W + px;
        float2 uo = su[ly][lx];
        u1Out[gi] = uo.x;
        u2Out[gi] = uo.y;
        if (!LASTWARP) {
          float2 pAo = spA[ly][lx];
          float2 pBo = spB[ly][lx];
          pOut[0 * N + gi] = pAo.x;
          pOut[1 * N + gi] = pBo.x;
          pOut[2 * N + gi] = pAo.y;
          pOut[3 * N + gi] = pBo.y;
        }
      }
    }
  }
}

extern "C" void kernel_launch(void* const* d_in, const int* in_sizes, int n_in,
                              void* d_out, int out_size, void* d_ws, size_t ws_size,
                              hipStream_t stream) {
  const float* x1 = (const float*)d_in[0];
  const float* x2 = (const float*)d_in[1];
  const float* u1_in = (const float*)d_in[2];
  const float* u2_in = (const float*)d_in[3];

  float* u1o  = (float*)d_out;
  float* u2o  = u1o + (size_t)N;
  float* rhoo = u1o + (size_t)2 * N;

  float* ws  = (float*)d_ws;
  float* uA1 = ws;
  float* uA2 = ws + (size_t)N;
  float* pA  = ws + (size_t)2 * N;   // 4N
  float* uB1 = ws + (size_t)6 * N;
  float* uB2 = ws + (size_t)7 * N;
  float* pB  = ws + (size_t)8 * N;   // 4N (total 12N floats = 88.5 MB)

  dim3 grd(NTX * NTY * B), blk(TPB);
  k_fused<0><<<grd, blk, 0, stream>>>(x1, x2, u1_in, u2_in, nullptr, uA1, uA2, pA, rhoo);
  k_fused<0><<<grd, blk, 0, stream>>>(x1, x2, uA1, uA2, pA, uB1, uB2, pB, rhoo);
  k_fused<0><<<grd, blk, 0, stream>>>(x1, x2, uB1, uB2, pB, uA1, uA2, pA, rhoo);
  k_fused<0><<<grd, blk, 0, stream>>>(x1, x2, uA1, uA2, pA, uB1, uB2, pB, rhoo);
  k_fused<1><<<grd, blk, 0, stream>>>(x1, x2, uB1, uB2, pB, u1o, u2o, pA, rhoo);
}